// Round 3
// baseline (861.510 us; speedup 1.0000x reference)
//
#include <hip/hip_runtime.h>
#include <hip/hip_bf16.h>
#include <cstdio>
#include <cstdint>

#define BB 8
#define NN 4096
#define FF 64

typedef __attribute__((ext_vector_type(8))) short bf16x8;
typedef __attribute__((ext_vector_type(4))) float f32x4;

__device__ __forceinline__ unsigned short f2bf(float f){
  unsigned int u = __float_as_uint(f);
  u += 0x7FFFu + ((u >> 16) & 1u);           // round-to-nearest-even
  return (unsigned short)(u >> 16);
}

__device__ __forceinline__ float leaky01(float x){ return x > 0.f ? x : 0.01f * x; }

// ---------------- pass 0: fp32 adj -> bf16 adj + row sums ----------------
__global__ __launch_bounds__(256) void k_convert(const float* __restrict__ adj,
    unsigned short* __restrict__ adjb, float* __restrict__ dinv, float* __restrict__ dsq)
{
  size_t row = blockIdx.x;                       // 0 .. BB*NN-1
  const float4* src = (const float4*)(adj + row * NN);
  ushort4* dst = (ushort4*)(adjb + row * NN);
  float s = 0.f;
  for (int i = threadIdx.x; i < NN / 4; i += 256){
    float4 v = src[i];
    s += (v.x + v.y) + (v.z + v.w);
    dst[i] = make_ushort4(f2bf(v.x), f2bf(v.y), f2bf(v.z), f2bf(v.w));
  }
  for (int o = 32; o; o >>= 1) s += __shfl_xor(s, o);
  __shared__ float red[4];
  if ((threadIdx.x & 63) == 0) red[threadIdx.x >> 6] = s;
  __syncthreads();
  if (threadIdx.x == 0){
    float t = (red[0] + red[1]) + (red[2] + red[3]);
    dinv[row] = 1.0f / t;                         // scattering: rowsum of adj
    dsq[row]  = 1.0f / sqrtf(t + 1.0f);           // gcn: rowsum(adj+I)^-1/2
  }
}

// ---------------- initial RHS (transposed, bf16): cols 0..63 = dsq*X, 64..127 = dinv*X ----
__global__ __launch_bounds__(256) void k_prep(const float* __restrict__ X,
    const float* __restrict__ dinv, const float* __restrict__ dsq,
    unsigned short* __restrict__ vt)
{
  const int b = blockIdx.y, n0 = blockIdx.x * 64, tid = threadIdx.x;
  __shared__ unsigned short tg[64][65], ts[64][65];
  #pragma unroll
  for (int i = 0; i < 4; ++i){
    int idx = i * 256 + tid, n = idx >> 4, c4 = (idx & 15) * 4;
    size_t rb = (size_t)b * NN + n0 + n;
    float4 x = *(const float4*)(X + rb * 64 + c4);
    float di = dinv[b * NN + n0 + n], dv = dsq[b * NN + n0 + n];
    tg[c4 + 0][n] = f2bf(dv * x.x); tg[c4 + 1][n] = f2bf(dv * x.y);
    tg[c4 + 2][n] = f2bf(dv * x.z); tg[c4 + 3][n] = f2bf(dv * x.w);
    ts[c4 + 0][n] = f2bf(di * x.x); ts[c4 + 1][n] = f2bf(di * x.y);
    ts[c4 + 2][n] = f2bf(di * x.z); ts[c4 + 3][n] = f2bf(di * x.w);
  }
  __syncthreads();
  #pragma unroll
  for (int i = 0; i < 4; ++i){
    int idx = i * 256 + tid, c = idx >> 4, n4 = (idx & 15) * 4;
    *(ushort4*)(vt + ((size_t)b * 128 + c) * NN + n0 + n4) =
        make_ushort4(tg[c][n4], tg[c][n4 + 1], tg[c][n4 + 2], tg[c][n4 + 3]);
    *(ushort4*)(vt + ((size_t)b * 128 + 64 + c) * NN + n0 + n4) =
        make_ushort4(ts[c][n4], ts[c][n4 + 1], ts[c][n4 + 2], ts[c][n4 + 3]);
  }
}

// ---------------- fused GEMM + epilogue, depth-3 pipeline ----------------
// Y[m, c] = sum_k adjb[b,m,k] * vtR[b, c0+c, k]; epilogue applies p-update /
// gcn-update in fp32 and writes the NEXT pass's transposed bf16 RHS into vtW.
// Triple-buffered LDS, prefetch distance 2, counted vmcnt (2 k-steps in flight).
template<int NC>
__global__ __launch_bounds__(256, NC == 128 ? 2 : 4) void k_gemm_fused(
    const unsigned short* __restrict__ adjb,
    const unsigned short* __restrict__ vtR, int c0,
    const float* __restrict__ sprev, float* __restrict__ P, float* __restrict__ snap,
    const float* __restrict__ dinv, int writeVtS,
    const float* __restrict__ gprev, float* __restrict__ gout,
    const float* __restrict__ dsq, int writeVtG,
    unsigned short* __restrict__ vtW)
{
  constexpr int NF = NC / 64;          // B n-frags per wave
  constexpr int BI = NC / 32;          // B staging issues per thread (ISS = 1 + BI)
  __shared__ __align__(16) unsigned short As[3][32 * 64];
  __shared__ __align__(16) unsigned short Bs[3][NC * 64];
  const int b = blockIdx.y;
  const int m0 = blockIdx.x * 32;
  const int tid = threadIdx.x;
  const int w = tid >> 6, l = tid & 63;
  const unsigned short* Ag = adjb + (size_t)b * NN * NN;
  const unsigned short* Bg = vtR + ((size_t)b * 128 + c0) * NN;

  auto stage = [&](int buf, int k0){
    {
      int r = tid >> 3, g = tid & 7;   // linear LDS dest; XOR-swizzle on GLOBAL source
      const unsigned short* gp = Ag + (size_t)(m0 + r) * NN + k0 + ((g ^ (r & 7)) << 3);
      __builtin_amdgcn_global_load_lds((const __attribute__((address_space(1))) void*)gp,
          (__attribute__((address_space(3))) void*)(&As[buf][tid << 3]), 16, 0, 0);
    }
    #pragma unroll
    for (int i = 0; i < BI; ++i){
      int idx = i * 256 + tid, c = idx >> 3, g = idx & 7;
      const unsigned short* gp = Bg + (size_t)c * NN + k0 + ((g ^ (c & 7)) << 3);
      __builtin_amdgcn_global_load_lds((const __attribute__((address_space(1))) void*)gp,
          (__attribute__((address_space(3))) void*)(&Bs[buf][idx << 3]), 16, 0, 0);
    }
  };

  f32x4 acc[2][NF];
  #pragma unroll
  for (int mi = 0; mi < 2; ++mi)
    #pragma unroll
    for (int ni = 0; ni < NF; ++ni)
      #pragma unroll
      for (int j = 0; j < 4; ++j) acc[mi][ni][j] = 0.f;

  stage(0, 0);
  stage(1, 64);
  const int r0 = l & 15, hq = l >> 4, sw = r0 & 7;
  constexpr int NT = NN / 64;
  int cur = 0, nxt2 = 2;
  for (int t = 0; t < NT; ++t){
    if (t + 2 < NT){
      stage(nxt2, (t + 2) * 64);
      if constexpr (NC == 128) asm volatile("s_waitcnt vmcnt(10)" ::: "memory");
      else                     asm volatile("s_waitcnt vmcnt(6)" ::: "memory");
    } else if (t + 1 < NT){
      if constexpr (NC == 128) asm volatile("s_waitcnt vmcnt(5)" ::: "memory");
      else                     asm volatile("s_waitcnt vmcnt(3)" ::: "memory");
    } else {
      asm volatile("s_waitcnt vmcnt(0)" ::: "memory");
    }
    __builtin_amdgcn_s_barrier();
    asm volatile("" ::: "memory");
    #pragma unroll
    for (int kk = 0; kk < 2; ++kk){
      const int g8 = ((kk * 4 + hq) ^ sw) << 3;
      bf16x8 af[2], bfr[NF];
      #pragma unroll
      for (int mi = 0; mi < 2; ++mi)
        af[mi] = *(const bf16x8*)&As[cur][(mi * 16 + r0) * 64 + g8];
      #pragma unroll
      for (int ni = 0; ni < NF; ++ni)
        bfr[ni] = *(const bf16x8*)&Bs[cur][(w * 16 * NF + ni * 16 + r0) * 64 + g8];
      #pragma unroll
      for (int mi = 0; mi < 2; ++mi)
        #pragma unroll
        for (int ni = 0; ni < NF; ++ni)
          acc[mi][ni] = __builtin_amdgcn_mfma_f32_16x16x32_bf16(af[mi], bfr[ni], acc[mi][ni], 0, 0, 0);
    }
    asm volatile("" ::: "memory");
    __builtin_amdgcn_s_barrier();
    asm volatile("" ::: "memory");
    cur = (cur == 2) ? 0 : cur + 1;
    nxt2 = (nxt2 == 2) ? 0 : nxt2 + 1;
  }

  // ---- fused epilogue: C/D layout col = lane&15 (r0), row = hq*4 + j ----
  const bool isScat = (NC == 64) || (w >= 2);
  if (isScat){
    const int wS = (NC == 64) ? w : (w - 2);
    #pragma unroll
    for (int mi = 0; mi < 2; ++mi){
      const int rb = m0 + mi * 16 + hq * 4;
      const size_t rowb = (size_t)b * NN + rb;
      float4 dv4 = *(const float4*)(dinv + (size_t)b * NN + rb);
      #pragma unroll
      for (int ni = 0; ni < NF; ++ni){
        const int cs = wS * 16 * NF + ni * 16 + r0;   // scat col 0..63
        float pn[4];
        #pragma unroll
        for (int j = 0; j < 4; ++j){
          float pv = sprev[(rowb + j) * 64 + cs];
          pn[j] = 0.5f * (pv + acc[mi][ni][j]);
          P[(rowb + j) * 64 + cs] = pn[j];
        }
        if (snap){
          #pragma unroll
          for (int j = 0; j < 4; ++j) snap[(rowb + j) * 64 + cs] = pn[j];
        }
        if (writeVtS){
          ushort4 vv = make_ushort4(f2bf(dv4.x * pn[0]), f2bf(dv4.y * pn[1]),
                                    f2bf(dv4.z * pn[2]), f2bf(dv4.w * pn[3]));
          *(ushort4*)(vtW + ((size_t)b * 128 + 64 + cs) * NN + rb) = vv;
        }
      }
    }
  }
  if constexpr (NC == 128){
    if (!isScat){                                     // gcn waves 0,1
      #pragma unroll
      for (int mi = 0; mi < 2; ++mi){
        const int rb = m0 + mi * 16 + hq * 4;
        const size_t rowb = (size_t)b * NN + rb;
        float4 dq4 = *(const float4*)(dsq + (size_t)b * NN + rb);
        #pragma unroll
        for (int ni = 0; ni < NF; ++ni){
          const int cg = w * 16 * NF + ni * 16 + r0;  // gcn col 0..63
          float hn[4];
          const float dq[4] = {dq4.x, dq4.y, dq4.z, dq4.w};
          #pragma unroll
          for (int j = 0; j < 4; ++j){
            float hv = gprev[(rowb + j) * 64 + cg];
            hn[j] = (acc[mi][ni][j] + dq[j] * hv) * dq[j];
            gout[(rowb + j) * 64 + cg] = hn[j];
          }
          if (writeVtG){
            ushort4 vv = make_ushort4(f2bf(dq[0] * hn[0]), f2bf(dq[1] * hn[1]),
                                      f2bf(dq[2] * hn[2]), f2bf(dq[3] * hn[3]));
            *(ushort4*)(vtW + ((size_t)b * 128 + cg) * NN + rb) = vv;
          }
        }
      }
    }
  }
}

// ---------------- attention over 6 branches + 2-layer MLP ----------------
__global__ __launch_bounds__(256) void k_attn(
    const float* __restrict__ X,  const float* __restrict__ hA, const float* __restrict__ hA2,
    const float* __restrict__ U1, const float* __restrict__ U2, const float* __restrict__ U4,
    const float* __restrict__ U8, const float* __restrict__ W1, const float* __restrict__ b1,
    const float* __restrict__ W2, const float* __restrict__ b2, const float* __restrict__ av,
    const int* __restrict__ momp, float* __restrict__ out)
{
  __shared__ float W1s[64][65], W2s[64][65];
  __shared__ float a1s[64], a2s[64], b1s[64], b2s[64];
  __shared__ float hp[4][64], o1[4][64];
  const int tid = threadIdx.x;
  for (int e = tid; e < 4096; e += 256){
    W1s[e >> 6][e & 63] = W1[e];
    W2s[e >> 6][e & 63] = W2[e];
  }
  if (tid < 64){ a1s[tid] = av[tid]; a2s[tid] = av[64 + tid]; b1s[tid] = b1[tid]; b2s[tid] = b2[tid]; }
  __syncthreads();
  const int w = tid >> 6, l = tid & 63;
  size_t row = (size_t)blockIdx.x * 4 + w;          // < BB*NN
  size_t off = row * 64 + l;
  float x  = X[off];
  float u1 = U1[off], u2 = U2[off], u4 = U4[off], u8 = U8[off];
  float br[6];
  br[0] = leaky01(hA[off]);
  br[1] = leaky01(hA2[off]);
  float d1 = fabsf(x - u1), d2 = fabsf(u1 - u2), d3 = fabsf(u2 - u4), d4 = fabsf(u4 - u8);
  int mom = *momp;
  if (mom == 1){ br[2] = d1; br[3] = d2; br[4] = d3; br[5] = d4; }
  else {
    float m = (float)mom;
    br[2] = powf(d1, m); br[3] = powf(d2, m); br[4] = powf(d3, m); br[5] = powf(d4, m);
  }
  float v = fmaxf(x, 0.f) * a1s[l];
  for (int o = 32; o; o >>= 1) v += __shfl_xor(v, o);
  float base = v;
  float e[6];
  #pragma unroll
  for (int k = 0; k < 6; ++k){
    float t = fmaxf(br[k], 0.f) * a2s[l];
    for (int o = 32; o; o >>= 1) t += __shfl_xor(t, o);
    e[k] = base + t;
  }
  float mx = e[0];
  #pragma unroll
  for (int k = 1; k < 6; ++k) mx = fmaxf(mx, e[k]);
  float s = 0.f, att[6];
  #pragma unroll
  for (int k = 0; k < 6; ++k){ att[k] = expf(e[k] - mx); s += att[k]; }
  float inv = 1.0f / (6.0f * s);
  float hpv = 0.f;
  #pragma unroll
  for (int k = 0; k < 6; ++k) hpv += att[k] * br[k];
  hpv *= inv;
  hp[w][l] = hpv;
  __syncthreads();
  float acc = b1s[l];
  #pragma unroll 8
  for (int c = 0; c < 64; ++c) acc += hp[w][c] * W1s[l][c];
  o1[w][l] = leaky01(acc);
  __syncthreads();
  float acc2 = b2s[l];
  #pragma unroll 8
  for (int c = 0; c < 64; ++c) acc2 += o1[w][c] * W2s[l][c];
  out[off] = leaky01(acc2);
}

// ---------------- workspace layout ----------------
static constexpr size_t OFF_ADJB = 0;                                   // bf16 [B][N][N]
static constexpr size_t OFF_VTA  = OFF_ADJB + (size_t)BB * NN * NN * 2; // bf16 [B][128][N]
static constexpr size_t OFF_VTB  = OFF_VTA  + (size_t)BB * 128 * NN * 2;
static constexpr size_t OFF_HA   = OFF_VTB  + (size_t)BB * 128 * NN * 2;
static constexpr size_t OFF_HA2  = OFF_HA   + (size_t)BB * NN * 64 * 4;
static constexpr size_t OFF_P    = OFF_HA2  + (size_t)BB * NN * 64 * 4;
static constexpr size_t OFF_U1   = OFF_P    + (size_t)BB * NN * 64 * 4;
static constexpr size_t OFF_U2   = OFF_U1   + (size_t)BB * NN * 64 * 4;
static constexpr size_t OFF_U4   = OFF_U2   + (size_t)BB * NN * 64 * 4;
static constexpr size_t OFF_U8   = OFF_U4   + (size_t)BB * NN * 64 * 4;
static constexpr size_t OFF_DINV = OFF_U8   + (size_t)BB * NN * 64 * 4;
static constexpr size_t OFF_DS   = OFF_DINV + (size_t)BB * NN * 4;
static constexpr size_t WS_NEED  = OFF_DS   + (size_t)BB * NN * 4;

extern "C" void kernel_launch(void* const* d_in, const int* in_sizes, int n_in,
                              void* d_out, int out_size, void* d_ws, size_t ws_size,
                              hipStream_t stream)
{
  const float* X   = (const float*)d_in[0];
  const float* adj = (const float*)d_in[1];
  const float* W1  = (const float*)d_in[2];
  const float* b1  = (const float*)d_in[3];
  const float* W2  = (const float*)d_in[4];
  const float* b2  = (const float*)d_in[5];
  const float* av  = (const float*)d_in[6];
  const int*  momp = (const int*)d_in[7];
  float* out = (float*)d_out;

  if (ws_size < WS_NEED){
    fprintf(stderr, "kernel_launch: workspace too small: %zu < %zu\n", ws_size, WS_NEED);
    return;
  }
  char* w = (char*)d_ws;
  unsigned short* adjb = (unsigned short*)(w + OFF_ADJB);
  unsigned short* vtA  = (unsigned short*)(w + OFF_VTA);
  unsigned short* vtB  = (unsigned short*)(w + OFF_VTB);
  float* hA   = (float*)(w + OFF_HA);
  float* hA2  = (float*)(w + OFF_HA2);
  float* P    = (float*)(w + OFF_P);
  float* U1   = (float*)(w + OFF_U1);
  float* U2   = (float*)(w + OFF_U2);
  float* U4   = (float*)(w + OFF_U4);
  float* U8   = (float*)(w + OFF_U8);
  float* dinv = (float*)(w + OFF_DINV);
  float* dsq  = (float*)(w + OFF_DS);

  k_convert<<<BB * NN, 256, 0, stream>>>(adj, adjb, dinv, dsq);
  dim3 tg64(NN / 64, BB);
  k_prep<<<tg64, 256, 0, stream>>>(X, dinv, dsq, vtA);

  dim3 gg(NN / 32, BB);
  // pass 1: dual RHS (gcn: dsq*X -> hA, scat: dinv*X -> P,U1); writes vtB (both halves)
  k_gemm_fused<128><<<gg, 256, 0, stream>>>(adjb, vtA, 0,
      X, P, U1, dinv, 1, X, hA, dsq, 1, vtB);
  // pass 2: dual RHS (gcn -> hA2, scat -> P,U2); writes vtA (scat half)
  k_gemm_fused<128><<<gg, 256, 0, stream>>>(adjb, vtB, 0,
      P, P, U2, dinv, 1, hA, hA2, dsq, 0, vtA);
  // passes 3..8: scattering only, alternate vtA/vtB
  unsigned short* vr = vtA;
  unsigned short* vw = vtB;
  for (int k = 3; k <= 8; ++k){
    float* snap = (k == 4) ? U4 : nullptr;
    float* pdst = (k == 8) ? U8 : P;
    k_gemm_fused<64><<<gg, 256, 0, stream>>>(adjb, vr, 64,
        P, pdst, snap, dinv, (k < 8) ? 1 : 0, nullptr, nullptr, nullptr, 0, vw);
    unsigned short* t = vr; vr = vw; vw = t;
  }

  k_attn<<<BB * NN / 4, 256, 0, stream>>>(X, hA, hA2, U1, U2, U4, U8,
                                          W1, b1, W2, b2, av, momp, out);
}

// Round 4
// 772.909 us; speedup vs baseline: 1.1146x; 1.1146x over previous
//
#include <hip/hip_runtime.h>
#include <hip/hip_bf16.h>
#include <cstdio>
#include <cstdint>

#define BB 8
#define NN 4096
#define FF 64

typedef __attribute__((ext_vector_type(8))) short bf16x8;
typedef __attribute__((ext_vector_type(4))) float f32x4;

__device__ __forceinline__ unsigned short f2bf(float f){
  unsigned int u = __float_as_uint(f);
  u += 0x7FFFu + ((u >> 16) & 1u);           // round-to-nearest-even
  return (unsigned short)(u >> 16);
}

__device__ __forceinline__ float leaky01(float x){ return x > 0.f ? x : 0.01f * x; }

// ---------------- pass 0: fp32 adj -> TILED+SWIZZLED bf16 A + row sums ----------------
// At[bid][t][idx*8 .. idx*8+8) = adj[b][m0+r][t*64 + ((g^(r&7))<<3) ..+8), idx=r*8+g.
// This is exactly the LDS image k_gemm stages, so the GEMM's A stream is CONTIGUOUS.
__global__ __launch_bounds__(256) void k_convert(const float* __restrict__ adj,
    unsigned short* __restrict__ At, float* __restrict__ dinv, float* __restrict__ dsq)
{
  const int bid = blockIdx.x;              // 1024 blocks; b = bid&7 (XCD-aligned), mt = bid>>3
  const int b = bid & 7, mt = bid >> 3, m0 = mt * 32;
  const int tid = threadIdx.x;
  const int r = tid >> 3, g = tid & 7;
  const float* src = adj + ((size_t)b * NN + m0 + r) * NN + ((g ^ (r & 7)) << 3);
  unsigned short* dst = At + (size_t)bid * 64 * 2048 + (tid << 3);
  float s = 0.f;
  for (int t = 0; t < 64; ++t){
    const float* p = src + t * 64;
    float4 a = *(const float4*)p;
    float4 c = *(const float4*)(p + 4);
    s += ((a.x + a.y) + (a.z + a.w)) + ((c.x + c.y) + (c.z + c.w));
    bf16x8 v;
    v[0] = (short)f2bf(a.x); v[1] = (short)f2bf(a.y); v[2] = (short)f2bf(a.z); v[3] = (short)f2bf(a.w);
    v[4] = (short)f2bf(c.x); v[5] = (short)f2bf(c.y); v[6] = (short)f2bf(c.z); v[7] = (short)f2bf(c.w);
    *(bf16x8*)(dst + (size_t)t * 2048) = v;
  }
  s += __shfl_xor(s, 1); s += __shfl_xor(s, 2); s += __shfl_xor(s, 4);
  if (g == 0){
    dinv[(size_t)b * NN + m0 + r] = 1.0f / s;            // scattering: rowsum of adj
    dsq [(size_t)b * NN + m0 + r] = 1.0f / sqrtf(s + 1.0f); // gcn: rowsum(adj+I)^-1/2
  }
}

// ---------------- initial RHS (transposed, bf16): cols 0..63 = dsq*X, 64..127 = dinv*X ----
__global__ __launch_bounds__(256) void k_prep(const float* __restrict__ X,
    const float* __restrict__ dinv, const float* __restrict__ dsq,
    unsigned short* __restrict__ vt)
{
  const int b = blockIdx.y, n0 = blockIdx.x * 64, tid = threadIdx.x;
  __shared__ unsigned short tg[64][65], ts[64][65];
  #pragma unroll
  for (int i = 0; i < 4; ++i){
    int idx = i * 256 + tid, n = idx >> 4, c4 = (idx & 15) * 4;
    size_t rb = (size_t)b * NN + n0 + n;
    float4 x = *(const float4*)(X + rb * 64 + c4);
    float di = dinv[b * NN + n0 + n], dv = dsq[b * NN + n0 + n];
    tg[c4 + 0][n] = f2bf(dv * x.x); tg[c4 + 1][n] = f2bf(dv * x.y);
    tg[c4 + 2][n] = f2bf(dv * x.z); tg[c4 + 3][n] = f2bf(dv * x.w);
    ts[c4 + 0][n] = f2bf(di * x.x); ts[c4 + 1][n] = f2bf(di * x.y);
    ts[c4 + 2][n] = f2bf(di * x.z); ts[c4 + 3][n] = f2bf(di * x.w);
  }
  __syncthreads();
  #pragma unroll
  for (int i = 0; i < 4; ++i){
    int idx = i * 256 + tid, c = idx >> 4, n4 = (idx & 15) * 4;
    *(ushort4*)(vt + ((size_t)b * 128 + c) * NN + n0 + n4) =
        make_ushort4(tg[c][n4], tg[c][n4 + 1], tg[c][n4 + 2], tg[c][n4 + 3]);
    *(ushort4*)(vt + ((size_t)b * 128 + 64 + c) * NN + n0 + n4) =
        make_ushort4(ts[c][n4], ts[c][n4 + 1], ts[c][n4 + 2], ts[c][n4 + 3]);
  }
}

// ---------------- fused GEMM + epilogue (depth-2, tiled-A) ----------------
// Y[m, c] = sum_k A[b,m,k] * vtR[b, c0+c, k]; A read from the contiguous tiled
// image At. Epilogue applies p-update / gcn-update in fp32 and writes the NEXT
// pass's transposed bf16 RHS into vtW. 1024 blocks, b = bid&7 (XCD-aligned).
template<int NC>
__global__ __launch_bounds__(256, 4) void k_gemm_fused(
    const unsigned short* __restrict__ At,
    const unsigned short* __restrict__ vtR, int c0,
    const float* __restrict__ sprev, float* __restrict__ P, float* __restrict__ snap,
    const float* __restrict__ dinv, int writeVtS,
    const float* __restrict__ gprev, float* __restrict__ gout,
    const float* __restrict__ dsq, int writeVtG,
    unsigned short* __restrict__ vtW)
{
  constexpr int NF = NC / 64;          // B n-frags per wave
  constexpr int BI = NC / 32;          // B staging issues per thread
  __shared__ __align__(16) unsigned short As[2][32 * 64];
  __shared__ __align__(16) unsigned short Bs[2][NC * 64];
  const int bid = blockIdx.x;
  const int b = bid & 7, mt = bid >> 3, m0 = mt * 32;
  const int tid = threadIdx.x;
  const int w = tid >> 6, l = tid & 63;
  const unsigned short* Atile = At + (size_t)bid * 64 * 2048;
  const unsigned short* Bg = vtR + ((size_t)b * 128 + c0) * NN;

  auto stage = [&](int buf, int t){
    {
      const unsigned short* gp = Atile + (size_t)t * 2048 + (tid << 3);  // contiguous stream
      __builtin_amdgcn_global_load_lds((const __attribute__((address_space(1))) void*)gp,
          (__attribute__((address_space(3))) void*)(&As[buf][tid << 3]), 16, 0, 0);
    }
    #pragma unroll
    for (int i = 0; i < BI; ++i){
      int idx = i * 256 + tid, c = idx >> 3, g = idx & 7;
      const unsigned short* gp = Bg + (size_t)c * NN + t * 64 + ((g ^ (c & 7)) << 3);
      __builtin_amdgcn_global_load_lds((const __attribute__((address_space(1))) void*)gp,
          (__attribute__((address_space(3))) void*)(&Bs[buf][idx << 3]), 16, 0, 0);
    }
  };

  f32x4 acc[2][NF];
  #pragma unroll
  for (int mi = 0; mi < 2; ++mi)
    #pragma unroll
    for (int ni = 0; ni < NF; ++ni)
      #pragma unroll
      for (int j = 0; j < 4; ++j) acc[mi][ni][j] = 0.f;

  stage(0, 0);
  const int r0 = l & 15, hq = l >> 4, sw = r0 & 7;
  constexpr int NT = NN / 64;
  for (int t = 0; t < NT; ++t){
    const int cur = t & 1;
    if (t + 1 < NT){
      stage(cur ^ 1, t + 1);
      if constexpr (NC == 128) asm volatile("s_waitcnt vmcnt(5)" ::: "memory");
      else                     asm volatile("s_waitcnt vmcnt(3)" ::: "memory");
    } else {
      asm volatile("s_waitcnt vmcnt(0)" ::: "memory");
    }
    __builtin_amdgcn_s_barrier();
    asm volatile("" ::: "memory");
    #pragma unroll
    for (int kk = 0; kk < 2; ++kk){
      const int g8 = ((kk * 4 + hq) ^ sw) << 3;
      bf16x8 af[2], bfr[NF];
      #pragma unroll
      for (int mi = 0; mi < 2; ++mi)
        af[mi] = *(const bf16x8*)&As[cur][(mi * 16 + r0) * 64 + g8];
      #pragma unroll
      for (int ni = 0; ni < NF; ++ni)
        bfr[ni] = *(const bf16x8*)&Bs[cur][(w * 16 * NF + ni * 16 + r0) * 64 + g8];
      #pragma unroll
      for (int mi = 0; mi < 2; ++mi)
        #pragma unroll
        for (int ni = 0; ni < NF; ++ni)
          acc[mi][ni] = __builtin_amdgcn_mfma_f32_16x16x32_bf16(af[mi], bfr[ni], acc[mi][ni], 0, 0, 0);
    }
    asm volatile("" ::: "memory");
    __builtin_amdgcn_s_barrier();
    asm volatile("" ::: "memory");
  }

  // ---- fused epilogue: C/D layout col = lane&15 (r0), row = hq*4 + j ----
  const bool isScat = (NC == 64) || (w >= 2);
  if (isScat){
    const int wS = (NC == 64) ? w : (w - 2);
    #pragma unroll
    for (int mi = 0; mi < 2; ++mi){
      const int rb = m0 + mi * 16 + hq * 4;
      const size_t rowb = (size_t)b * NN + rb;
      float4 dv4 = *(const float4*)(dinv + (size_t)b * NN + rb);
      #pragma unroll
      for (int ni = 0; ni < NF; ++ni){
        const int cs = wS * 16 * NF + ni * 16 + r0;   // scat col 0..63
        float pn[4];
        #pragma unroll
        for (int j = 0; j < 4; ++j){
          float pv = sprev[(rowb + j) * 64 + cs];
          pn[j] = 0.5f * (pv + acc[mi][ni][j]);
          P[(rowb + j) * 64 + cs] = pn[j];
        }
        if (snap){
          #pragma unroll
          for (int j = 0; j < 4; ++j) snap[(rowb + j) * 64 + cs] = pn[j];
        }
        if (writeVtS){
          ushort4 vv = make_ushort4(f2bf(dv4.x * pn[0]), f2bf(dv4.y * pn[1]),
                                    f2bf(dv4.z * pn[2]), f2bf(dv4.w * pn[3]));
          *(ushort4*)(vtW + ((size_t)b * 128 + 64 + cs) * NN + rb) = vv;
        }
      }
    }
  }
  if constexpr (NC == 128){
    if (!isScat){                                     // gcn waves 0,1
      #pragma unroll
      for (int mi = 0; mi < 2; ++mi){
        const int rb = m0 + mi * 16 + hq * 4;
        const size_t rowb = (size_t)b * NN + rb;
        float4 dq4 = *(const float4*)(dsq + (size_t)b * NN + rb);
        #pragma unroll
        for (int ni = 0; ni < NF; ++ni){
          const int cg = w * 16 * NF + ni * 16 + r0;  // gcn col 0..63
          float hn[4];
          const float dq[4] = {dq4.x, dq4.y, dq4.z, dq4.w};
          #pragma unroll
          for (int j = 0; j < 4; ++j){
            float hv = gprev[(rowb + j) * 64 + cg];
            hn[j] = (acc[mi][ni][j] + dq[j] * hv) * dq[j];
            gout[(rowb + j) * 64 + cg] = hn[j];
          }
          if (writeVtG){
            ushort4 vv = make_ushort4(f2bf(dq[0] * hn[0]), f2bf(dq[1] * hn[1]),
                                      f2bf(dq[2] * hn[2]), f2bf(dq[3] * hn[3]));
            *(ushort4*)(vtW + ((size_t)b * 128 + cg) * NN + rb) = vv;
          }
        }
      }
    }
  }
}

// ---------------- attention over 6 branches + 2-layer MLP ----------------
__global__ __launch_bounds__(256) void k_attn(
    const float* __restrict__ X,  const float* __restrict__ hA, const float* __restrict__ hA2,
    const float* __restrict__ U1, const float* __restrict__ U2, const float* __restrict__ U4,
    const float* __restrict__ U8, const float* __restrict__ W1, const float* __restrict__ b1,
    const float* __restrict__ W2, const float* __restrict__ b2, const float* __restrict__ av,
    const int* __restrict__ momp, float* __restrict__ out)
{
  __shared__ float W1s[64][65], W2s[64][65];
  __shared__ float a1s[64], a2s[64], b1s[64], b2s[64];
  __shared__ float hp[4][64], o1[4][64];
  const int tid = threadIdx.x;
  for (int e = tid; e < 4096; e += 256){
    W1s[e >> 6][e & 63] = W1[e];
    W2s[e >> 6][e & 63] = W2[e];
  }
  if (tid < 64){ a1s[tid] = av[tid]; a2s[tid] = av[64 + tid]; b1s[tid] = b1[tid]; b2s[tid] = b2[tid]; }
  __syncthreads();
  const int w = tid >> 6, l = tid & 63;
  size_t row = (size_t)blockIdx.x * 4 + w;          // < BB*NN
  size_t off = row * 64 + l;
  float x  = X[off];
  float u1 = U1[off], u2 = U2[off], u4 = U4[off], u8 = U8[off];
  float br[6];
  br[0] = leaky01(hA[off]);
  br[1] = leaky01(hA2[off]);
  float d1 = fabsf(x - u1), d2 = fabsf(u1 - u2), d3 = fabsf(u2 - u4), d4 = fabsf(u4 - u8);
  int mom = *momp;
  if (mom == 1){ br[2] = d1; br[3] = d2; br[4] = d3; br[5] = d4; }
  else {
    float m = (float)mom;
    br[2] = powf(d1, m); br[3] = powf(d2, m); br[4] = powf(d3, m); br[5] = powf(d4, m);
  }
  float v = fmaxf(x, 0.f) * a1s[l];
  for (int o = 32; o; o >>= 1) v += __shfl_xor(v, o);
  float base = v;
  float e[6];
  #pragma unroll
  for (int k = 0; k < 6; ++k){
    float t = fmaxf(br[k], 0.f) * a2s[l];
    for (int o = 32; o; o >>= 1) t += __shfl_xor(t, o);
    e[k] = base + t;
  }
  float mx = e[0];
  #pragma unroll
  for (int k = 1; k < 6; ++k) mx = fmaxf(mx, e[k]);
  float s = 0.f, att[6];
  #pragma unroll
  for (int k = 0; k < 6; ++k){ att[k] = expf(e[k] - mx); s += att[k]; }
  float inv = 1.0f / (6.0f * s);
  float hpv = 0.f;
  #pragma unroll
  for (int k = 0; k < 6; ++k) hpv += att[k] * br[k];
  hpv *= inv;
  hp[w][l] = hpv;
  __syncthreads();
  float acc = b1s[l];
  #pragma unroll 8
  for (int c = 0; c < 64; ++c) acc += hp[w][c] * W1s[l][c];
  o1[w][l] = leaky01(acc);
  __syncthreads();
  float acc2 = b2s[l];
  #pragma unroll 8
  for (int c = 0; c < 64; ++c) acc2 += o1[w][c] * W2s[l][c];
  out[off] = leaky01(acc2);
}

// ---------------- workspace layout ----------------
static constexpr size_t OFF_ADJB = 0;                                   // bf16 tiled A
static constexpr size_t OFF_VTA  = OFF_ADJB + (size_t)BB * NN * NN * 2; // bf16 [B][128][N]
static constexpr size_t OFF_VTB  = OFF_VTA  + (size_t)BB * 128 * NN * 2;
static constexpr size_t OFF_HA   = OFF_VTB  + (size_t)BB * 128 * NN * 2;
static constexpr size_t OFF_HA2  = OFF_HA   + (size_t)BB * NN * 64 * 4;
static constexpr size_t OFF_P    = OFF_HA2  + (size_t)BB * NN * 64 * 4;
static constexpr size_t OFF_U1   = OFF_P    + (size_t)BB * NN * 64 * 4;
static constexpr size_t OFF_U2   = OFF_U1   + (size_t)BB * NN * 64 * 4;
static constexpr size_t OFF_U4   = OFF_U2   + (size_t)BB * NN * 64 * 4;
static constexpr size_t OFF_U8   = OFF_U4   + (size_t)BB * NN * 64 * 4;
static constexpr size_t OFF_DINV = OFF_U8   + (size_t)BB * NN * 64 * 4;
static constexpr size_t OFF_DS   = OFF_DINV + (size_t)BB * NN * 4;
static constexpr size_t WS_NEED  = OFF_DS   + (size_t)BB * NN * 4;

extern "C" void kernel_launch(void* const* d_in, const int* in_sizes, int n_in,
                              void* d_out, int out_size, void* d_ws, size_t ws_size,
                              hipStream_t stream)
{
  const float* X   = (const float*)d_in[0];
  const float* adj = (const float*)d_in[1];
  const float* W1  = (const float*)d_in[2];
  const float* b1  = (const float*)d_in[3];
  const float* W2  = (const float*)d_in[4];
  const float* b2  = (const float*)d_in[5];
  const float* av  = (const float*)d_in[6];
  const int*  momp = (const int*)d_in[7];
  float* out = (float*)d_out;

  if (ws_size < WS_NEED){
    fprintf(stderr, "kernel_launch: workspace too small: %zu < %zu\n", ws_size, WS_NEED);
    return;
  }
  char* w = (char*)d_ws;
  unsigned short* At  = (unsigned short*)(w + OFF_ADJB);
  unsigned short* vtA = (unsigned short*)(w + OFF_VTA);
  unsigned short* vtB = (unsigned short*)(w + OFF_VTB);
  float* hA   = (float*)(w + OFF_HA);
  float* hA2  = (float*)(w + OFF_HA2);
  float* P    = (float*)(w + OFF_P);
  float* U1   = (float*)(w + OFF_U1);
  float* U2   = (float*)(w + OFF_U2);
  float* U4   = (float*)(w + OFF_U4);
  float* U8   = (float*)(w + OFF_U8);
  float* dinv = (float*)(w + OFF_DINV);
  float* dsq  = (float*)(w + OFF_DS);

  k_convert<<<1024, 256, 0, stream>>>(adj, At, dinv, dsq);
  dim3 tg64(NN / 64, BB);
  k_prep<<<tg64, 256, 0, stream>>>(X, dinv, dsq, vtA);

  // pass 1: dual RHS (gcn: dsq*X -> hA, scat: dinv*X -> P,U1); writes vtB (both halves)
  k_gemm_fused<128><<<1024, 256, 0, stream>>>(At, vtA, 0,
      X, P, U1, dinv, 1, X, hA, dsq, 1, vtB);
  // pass 2: dual RHS (gcn -> hA2, scat -> P,U2); writes vtA (scat half)
  k_gemm_fused<128><<<1024, 256, 0, stream>>>(At, vtB, 0,
      P, P, U2, dinv, 1, hA, hA2, dsq, 0, vtA);
  // passes 3..8: scattering only, alternate vtA/vtB
  unsigned short* vr = vtA;
  unsigned short* vw = vtB;
  for (int k = 3; k <= 8; ++k){
    float* snap = (k == 4) ? U4 : nullptr;
    float* pdst = (k == 8) ? U8 : P;
    k_gemm_fused<64><<<1024, 256, 0, stream>>>(At, vr, 64,
        P, pdst, snap, dinv, (k < 8) ? 1 : 0, nullptr, nullptr, nullptr, 0, vw);
    unsigned short* t = vr; vr = vw; vw = t;
  }

  k_attn<<<BB * NN / 4, 256, 0, stream>>>(X, hA, hA2, U1, U2, U4, U8,
                                          W1, b1, W2, b2, av, momp, out);
}